// Round 1
// 228.052 us; speedup vs baseline: 1.0221x; 1.0221x over previous
//
#include <hip/hip_runtime.h>
#include <hip/hip_bf16.h>
#include <cstdint>
#include <cstddef>

// Problem shape (fixed): x [B=16][N=2048][D=512] fp32
#define BB 16
#define NN 2048
#define DD 512

typedef _Float16 f16x8 __attribute__((ext_vector_type(8)));
typedef _Float16 f16x4 __attribute__((ext_vector_type(4)));
typedef float f32x4 __attribute__((ext_vector_type(4)));

// Async global->LDS, 16 B per lane. LDS dest = wave-uniform base + lane*16.
__device__ __forceinline__ void async_ld16(void* lds, const void* g) {
    __builtin_amdgcn_global_load_lds(
        (const __attribute__((address_space(1))) unsigned int*)(uintptr_t)g,
        (__attribute__((address_space(3))) unsigned int*)(uint32_t)(uintptr_t)lds,
        16, 0, 0);
}

// ---------------------------------------------------------------------------
// K1 (fused): read x ONCE. Per 64-row slab:
//   - per-row L2 norm (fp32 exact, wave shuffle reduce)
//   - xhn = normalized rows, fp16, row-major   (for k_scores: S = xhn xhn^T)
//   - vT  = unnormalized fp16 transpose [b][d][j] via LDS (for k_pv B-operand)
//   - denom zero-init
// grid (NN/64, BB), 256 threads. LDS 512x66 fp16 = 66 KB -> 2 blocks/CU.
// ---------------------------------------------------------------------------
__global__ __launch_bounds__(256) void k_prep(const float* __restrict__ x,
                                              _Float16* __restrict__ xhn,
                                              _Float16* __restrict__ vT,
                                              float* __restrict__ denom) {
    __shared__ _Float16 t[512 * 66];     // [d][j], pitch 66 halves
    const int tid = threadIdx.x, lane = tid & 63, w = tid >> 6;
    const int b = blockIdx.y, j0 = blockIdx.x * 64;
    if (tid < 64) denom[b * NN + j0 + tid] = 0.f;
    const float* xb = x + ((size_t)b * NN + j0) * DD;

    for (int rr = 0; rr < 16; ++rr) {
        const int jj = w * 16 + rr;                 // row within slab
        const float* xr = xb + (size_t)jj * DD;
        float4 a = ((const float4*)xr)[lane];       // d = 4*lane ..
        float4 c = ((const float4*)xr)[lane + 64];  // d = 256+4*lane ..
        float ss = a.x*a.x + a.y*a.y + a.z*a.z + a.w*a.w
                 + c.x*c.x + c.y*c.y + c.z*c.z + c.w*c.w;
        #pragma unroll
        for (int o = 1; o < 64; o <<= 1) ss += __shfl_xor(ss, o);
        const float rn = 1.0f / sqrtf(ss);
        // normalized fp16 row (coalesced 8B stores)
        _Float16* dst = xhn + ((size_t)b * NN + j0 + jj) * DD;
        f16x4 v0 = {(_Float16)(a.x*rn), (_Float16)(a.y*rn), (_Float16)(a.z*rn), (_Float16)(a.w*rn)};
        f16x4 v1 = {(_Float16)(c.x*rn), (_Float16)(c.y*rn), (_Float16)(c.z*rn), (_Float16)(c.w*rn)};
        *(f16x4*)(dst + 4 * lane) = v0;
        *(f16x4*)(dst + 256 + 4 * lane) = v1;
        // unnormalized fp16 into transposed LDS tile
        const int d0 = 4 * lane, d1 = 256 + 4 * lane;
        t[(d0 + 0) * 66 + jj] = (_Float16)a.x;
        t[(d0 + 1) * 66 + jj] = (_Float16)a.y;
        t[(d0 + 2) * 66 + jj] = (_Float16)a.z;
        t[(d0 + 3) * 66 + jj] = (_Float16)a.w;
        t[(d1 + 0) * 66 + jj] = (_Float16)c.x;
        t[(d1 + 1) * 66 + jj] = (_Float16)c.y;
        t[(d1 + 2) * 66 + jj] = (_Float16)c.z;
        t[(d1 + 3) * 66 + jj] = (_Float16)c.w;
    }
    __syncthreads();
    // store vT rows: 512 d x 8 chunks of 8 halves; 4B-aligned b32 LDS reads.
    #pragma unroll
    for (int it = 0; it < 16; ++it) {
        const int id = it * 256 + tid;
        const int d = id >> 3, ch = (id & 7) * 8;
        const uint32_t* tp = (const uint32_t*)&t[d * 66 + ch];
        uint4 v = {tp[0], tp[1], tp[2], tp[3]};
        *(uint4*)(vT + ((size_t)b * DD + d) * NN + j0 + ch) = v;
    }
}

// ---------------------------------------------------------------------------
// K2: W = exp( xhn xhn^T ), symmetric-triangular (inputs pre-normalized).
// GEMM: async swizzled staging, 128x128 block, 4 waves 64x64, BK=64.
// NEW: double-buffered 2-phase staging (T3-min): issue next K-step's
// global_load_lds BEFORE current step's ds_read+MFMA, so load latency hides
// under compute; one barrier per step drains the residual.
// Epilogue: two-phase (col-major b64 -> W(J,I); row-major scalar -> W(I,J)).
// Row/col sums of quantized W -> denom via register butterflies + atomics.
// ---------------------------------------------------------------------------
__global__ __launch_bounds__(256) void k_scores(const _Float16* __restrict__ xhn,
                                                _Float16* __restrict__ W,
                                                float* __restrict__ denom) {
    __shared__ _Float16 smem[32768];          // 2 x (As 8192 + Bs 8192); epi: 128x136
    const int tid = threadIdx.x;
    const int lane = tid & 63, wv = tid >> 6;
    const int wr = wv >> 1, wc = wv & 1;
    const int m_ = lane & 15, quad = lane >> 4;
    const int b = blockIdx.z;

    int rem = blockIdx.x, ti = 0, rowlen = NN / 128;
    while (rem >= rowlen) { rem -= rowlen; ++ti; --rowlen; }
    const int tj = ti + rem;
    const int I = ti * 128, J = tj * 128;
    const bool diag = (ti == tj);

    const _Float16* Ab = xhn + ((size_t)b * NN + I) * DD;
    const _Float16* Bb = xhn + ((size_t)b * NN + J) * DD;

    f32x4 acc[4][4];
    #pragma unroll
    for (int i = 0; i < 4; ++i)
        #pragma unroll
        for (int j = 0; j < 4; ++j) acc[i][j] = (f32x4){0.f, 0.f, 0.f, 0.f};

    const int sub = lane >> 3;
    const int swc = (lane & 7) ^ sub;
    const _Float16* agl = Ab + (size_t)(wv * 32 + sub) * DD + swc * 8;
    const _Float16* bgl = Bb + (size_t)(wv * 32 + sub) * DD + swc * 8;

    // prologue: stage kb=0 into buffer 0
    #pragma unroll
    for (int c = 0; c < 4; ++c) {
        async_ld16(&smem[(wv * 32 + c * 8) * 64], agl + (size_t)c * 8 * DD);
        async_ld16(&smem[8192 + (wv * 32 + c * 8) * 64], bgl + (size_t)c * 8 * DD);
    }
    __syncthreads();

    int cur = 0;
    for (int kb = 0; kb < DD / 64; ++kb) {
        const _Float16* As = smem + cur * 16384;
        const _Float16* Bs = As + 8192;
        // issue next step's loads into the other buffer (overlaps MFMA below)
        if (kb + 1 < DD / 64) {
            const int kn = (kb + 1) * 64;
            _Float16* An = smem + (cur ^ 1) * 16384;
            #pragma unroll
            for (int c = 0; c < 4; ++c) {
                async_ld16(&An[(wv * 32 + c * 8) * 64], agl + (size_t)c * 8 * DD + kn);
                async_ld16(&An[8192 + (wv * 32 + c * 8) * 64], bgl + (size_t)c * 8 * DD + kn);
            }
        }
        #pragma unroll
        for (int kc = 0; kc < 2; ++kc) {
            f16x8 af[4], bf[4];
            #pragma unroll
            for (int t = 0; t < 4; ++t) {
                const int Ra = wr * 64 + t * 16 + m_;
                const int Rb = wc * 64 + t * 16 + m_;
                af[t] = *(const f16x8*)&As[Ra * 64 + (((kc * 4 + quad) ^ (Ra & 7)) * 8)];
                bf[t] = *(const f16x8*)&Bs[Rb * 64 + (((kc * 4 + quad) ^ (Rb & 7)) * 8)];
            }
            #pragma unroll
            for (int i = 0; i < 4; ++i)
                #pragma unroll
                for (int j = 0; j < 4; ++j)
                    acc[i][j] = __builtin_amdgcn_mfma_f32_16x16x32_f16(af[i], bf[j], acc[i][j], 0, 0, 0);
        }
        __syncthreads();   // drains vmcnt(0): next buffer ready; readers done
        cur ^= 1;
    }

    // Epilogue: exp into packed f16x4; register row/col sums.
    f16x4 wq[4][4];
    float rowpart[4][4];
    float colpart[4] = {0.f, 0.f, 0.f, 0.f};
    #pragma unroll
    for (int i = 0; i < 4; ++i)
        #pragma unroll
        for (int r = 0; r < 4; ++r) rowpart[i][r] = 0.f;

    #pragma unroll
    for (int i = 0; i < 4; ++i) {
        #pragma unroll
        for (int j = 0; j < 4; ++j) {
            #pragma unroll
            for (int r = 0; r < 4; ++r) {
                const float w = __expf(acc[i][j][r]);
                wq[i][j][r] = (_Float16)w;
                rowpart[i][r] += w;
                colpart[j] += w;
            }
        }
    }

    #pragma unroll
    for (int i = 0; i < 4; ++i) {
        #pragma unroll
        for (int r = 0; r < 4; ++r) {
            float s = rowpart[i][r];
            s += __shfl_xor(s, 1);
            s += __shfl_xor(s, 2);
            s += __shfl_xor(s, 4);
            s += __shfl_xor(s, 8);
            if (m_ == 0)
                atomicAdd(&denom[b * NN + I + wr * 64 + i * 16 + quad * 4 + r], s);
        }
    }
    if (!diag) {
        #pragma unroll
        for (int j = 0; j < 4; ++j) {
            float s = colpart[j];
            s += __shfl_xor(s, 16);
            s += __shfl_xor(s, 32);
            if (quad == 0)
                atomicAdd(&denom[b * NN + J + wc * 64 + j * 16 + m_], s);
        }
    }

    // Phase 1: WtT[col][row] (stride 136), b64 writes -> coalesced W(J,I).
    _Float16* WtT = smem;
    #pragma unroll
    for (int i = 0; i < 4; ++i) {
        const int rowb = wr * 64 + i * 16 + quad * 4;
        #pragma unroll
        for (int j = 0; j < 4; ++j) {
            const int col = wc * 64 + j * 16 + m_;
            *(f16x4*)&WtT[col * 136 + rowb] = wq[i][j];
        }
    }
    __syncthreads();
    {
        const int rr = tid >> 1, off = (tid & 1) * 64;
        _Float16* wg = W + ((size_t)b * NN + J + rr) * NN + I + off;
        const _Float16* wl = &WtT[rr * 136 + off];
        #pragma unroll
        for (int c = 0; c < 64; c += 8)
            *(uint4*)(wg + c) = *(const uint4*)(wl + c);
    }
    // Phase 2 (off-diag): row-major Wt -> coalesced W(I,J).
    if (!diag) {
        __syncthreads();
        _Float16* Wt = smem;
        #pragma unroll
        for (int i = 0; i < 4; ++i) {
            const int rowb = wr * 64 + i * 16 + quad * 4;
            #pragma unroll
            for (int j = 0; j < 4; ++j) {
                const int col = wc * 64 + j * 16 + m_;
                #pragma unroll
                for (int r = 0; r < 4; ++r)
                    Wt[(rowb + r) * 136 + col] = wq[i][j][r];
            }
        }
        __syncthreads();
        const int rr = tid >> 1, off = (tid & 1) * 64;
        _Float16* wg = W + ((size_t)b * NN + I + rr) * NN + J + off;
        const _Float16* wl = &Wt[rr * 136 + off];
        #pragma unroll
        for (int c = 0; c < 64; c += 8)
            *(uint4*)(wg + c) = *(const uint4*)(wl + c);
    }
}

// ---------------------------------------------------------------------------
// K3: O = (W @ V) * (1/denom_i), fp32 out.
// NEW: (a) same 2-phase double-buffered staging as k_scores (32 K-steps of
// HBM/L3-latency W reads now overlap MFMA); (b) grid transposed so the 4
// D-chunk blocks sharing one W A-panel are dispatch-adjacent (panel served
// from L3 once instead of 4 HBM refetches).
// grid (D/128, N/128, B), 256 threads.
// ---------------------------------------------------------------------------
__global__ __launch_bounds__(256) void k_pv(const _Float16* __restrict__ W,
                                            const _Float16* __restrict__ vT,
                                            const float* __restrict__ denom,
                                            float* __restrict__ out) {
    __shared__ _Float16 smem[32768];          // 2 x (As 8192 + Bs 8192)
    __shared__ float rdI[128];
    const int tid = threadIdx.x;
    const int lane = tid & 63, wv = tid >> 6;
    const int wr = wv >> 1, wc = wv & 1;
    const int m_ = lane & 15, quad = lane >> 4;
    const int rm = m_ & 7;
    const int b = blockIdx.z;
    const int I = blockIdx.y * 128;
    const int D0 = blockIdx.x * 128;
    const _Float16* Ab = W + ((size_t)b * NN + I) * NN;
    const _Float16* Bb = vT + ((size_t)b * DD + D0) * NN;
    if (tid < 128) rdI[tid] = 1.0f / denom[b * NN + I + tid];

    f32x4 acc[4][4];
    #pragma unroll
    for (int i = 0; i < 4; ++i)
        #pragma unroll
        for (int j = 0; j < 4; ++j) acc[i][j] = (f32x4){0.f, 0.f, 0.f, 0.f};

    const int sub = lane >> 3;
    const int swc = (lane & 7) ^ sub;
    const _Float16* agl = Ab + (size_t)(wv * 32 + sub) * NN + swc * 8;
    const _Float16* bgl = Bb + (size_t)(wv * 32 + sub) * NN + swc * 8;

    // prologue: stage kb=0 into buffer 0
    #pragma unroll
    for (int c = 0; c < 4; ++c) {
        async_ld16(&smem[(wv * 32 + c * 8) * 64], agl + (size_t)c * 8 * NN);
        async_ld16(&smem[8192 + (wv * 32 + c * 8) * 64], bgl + (size_t)c * 8 * NN);
    }
    __syncthreads();

    int cur = 0;
    for (int kb = 0; kb < NN / 64; ++kb) {
        const _Float16* As = smem + cur * 16384;
        const _Float16* Bs = As + 8192;
        if (kb + 1 < NN / 64) {
            const int kn = (kb + 1) * 64;
            _Float16* An = smem + (cur ^ 1) * 16384;
            #pragma unroll
            for (int c = 0; c < 4; ++c) {
                async_ld16(&An[(wv * 32 + c * 8) * 64], agl + (size_t)c * 8 * NN + kn);
                async_ld16(&An[8192 + (wv * 32 + c * 8) * 64], bgl + (size_t)c * 8 * NN + kn);
            }
        }
        #pragma unroll
        for (int kc = 0; kc < 2; ++kc) {
            f16x8 af[4], bf[4];
            #pragma unroll
            for (int t = 0; t < 4; ++t) {
                const int ko = ((kc * 4 + quad) ^ rm) * 8;
                af[t] = *(const f16x8*)&As[(wr * 64 + t * 16 + m_) * 64 + ko];
                bf[t] = *(const f16x8*)&Bs[(wc * 64 + t * 16 + m_) * 64 + ko];
            }
            #pragma unroll
            for (int i = 0; i < 4; ++i)
                #pragma unroll
                for (int j = 0; j < 4; ++j)
                    acc[i][j] = __builtin_amdgcn_mfma_f32_16x16x32_f16(af[i], bf[j], acc[i][j], 0, 0, 0);
        }
        __syncthreads();
        cur ^= 1;
    }

    #pragma unroll
    for (int i = 0; i < 4; ++i) {
        const int rowb = wr * 64 + i * 16 + quad * 4;
        #pragma unroll
        for (int r = 0; r < 4; ++r) {
            const float sc = rdI[rowb + r];
            float* op = out + ((size_t)(b * NN + I + rowb + r)) * DD + D0;
            #pragma unroll
            for (int j = 0; j < 4; ++j)
                op[wc * 64 + j * 16 + m_] = acc[i][j][r] * sc;
        }
    }
}

// ---------------------------------------------------------------------------
extern "C" void kernel_launch(void* const* d_in, const int* in_sizes, int n_in,
                              void* d_out, int out_size, void* d_ws, size_t ws_size,
                              hipStream_t stream) {
    const float* x = (const float*)d_in[0];
    char* ws = (char*)d_ws;
    _Float16* xhn   = (_Float16*)(ws);                        // 32 MiB normalized fp16
    _Float16* vT    = (_Float16*)(ws + (size_t)33554432);     // 32 MiB fp16 x^T
    _Float16* W     = (_Float16*)(ws + (size_t)67108864);     // 128 MiB fp16 exp-scores
    float*    denom = (float*)   (ws + (size_t)201326592);    // 128 KiB
    float*    out   = (float*)d_out;

    k_prep<<<dim3(NN / 64, BB), 256, 0, stream>>>(x, xhn, vT, denom);
    const int npairs = (NN / 128) * (NN / 128 + 1) / 2;   // 136
    k_scores<<<dim3(npairs, 1, BB), 256, 0, stream>>>(xhn, W, denom);
    k_pv<<<dim3(DD / 128, NN / 128, BB), 256, 0, stream>>>(W, vT, denom, out);
}

// Round 2
// 206.711 us; speedup vs baseline: 1.1276x; 1.1032x over previous
//
#include <hip/hip_runtime.h>
#include <hip/hip_bf16.h>
#include <cstdint>
#include <cstddef>

// Problem shape (fixed): x [B=16][N=2048][D=512] fp32
#define BB 16
#define NN 2048
#define DD 512

typedef _Float16 f16x8 __attribute__((ext_vector_type(8)));
typedef _Float16 f16x4 __attribute__((ext_vector_type(4)));
typedef float f32x4 __attribute__((ext_vector_type(4)));

// Async global->LDS, 16 B per lane. LDS dest = wave-uniform base + lane*16.
__device__ __forceinline__ void async_ld16(void* lds, const void* g) {
    __builtin_amdgcn_global_load_lds(
        (const __attribute__((address_space(1))) unsigned int*)(uintptr_t)g,
        (__attribute__((address_space(3))) unsigned int*)(uint32_t)(uintptr_t)lds,
        16, 0, 0);
}

#define VM_WAIT(n) asm volatile("s_waitcnt vmcnt(" #n ")" ::: "memory")
#define RAW_BAR()  do { asm volatile("" ::: "memory"); __builtin_amdgcn_s_barrier(); asm volatile("" ::: "memory"); } while (0)

// ---------------------------------------------------------------------------
// K1 (fused): read x ONCE. Per 64-row slab:
//   - per-row L2 norm (fp32 exact, wave shuffle reduce)
//   - xhn = normalized rows, fp16, row-major   (for k_scores: S = xhn xhn^T)
//   - vT  = unnormalized fp16 transpose [b][d][j] via LDS (for k_pv B-operand)
//   - denom zero-init
// grid (NN/64, BB), 256 threads.
// ---------------------------------------------------------------------------
__global__ __launch_bounds__(256) void k_prep(const float* __restrict__ x,
                                              _Float16* __restrict__ xhn,
                                              _Float16* __restrict__ vT,
                                              float* __restrict__ denom) {
    __shared__ _Float16 t[512 * 66];     // [d][j], pitch 66 halves
    const int tid = threadIdx.x, lane = tid & 63, w = tid >> 6;
    const int b = blockIdx.y, j0 = blockIdx.x * 64;
    if (tid < 64) denom[b * NN + j0 + tid] = 0.f;
    const float* xb = x + ((size_t)b * NN + j0) * DD;

    for (int rr = 0; rr < 16; ++rr) {
        const int jj = w * 16 + rr;                 // row within slab
        const float* xr = xb + (size_t)jj * DD;
        float4 a = ((const float4*)xr)[lane];       // d = 4*lane ..
        float4 c = ((const float4*)xr)[lane + 64];  // d = 256+4*lane ..
        float ss = a.x*a.x + a.y*a.y + a.z*a.z + a.w*a.w
                 + c.x*c.x + c.y*c.y + c.z*c.z + c.w*c.w;
        #pragma unroll
        for (int o = 1; o < 64; o <<= 1) ss += __shfl_xor(ss, o);
        const float rn = 1.0f / sqrtf(ss);
        // normalized fp16 row (coalesced 8B stores)
        _Float16* dst = xhn + ((size_t)b * NN + j0 + jj) * DD;
        f16x4 v0 = {(_Float16)(a.x*rn), (_Float16)(a.y*rn), (_Float16)(a.z*rn), (_Float16)(a.w*rn)};
        f16x4 v1 = {(_Float16)(c.x*rn), (_Float16)(c.y*rn), (_Float16)(c.z*rn), (_Float16)(c.w*rn)};
        *(f16x4*)(dst + 4 * lane) = v0;
        *(f16x4*)(dst + 256 + 4 * lane) = v1;
        // unnormalized fp16 into transposed LDS tile
        const int d0 = 4 * lane, d1 = 256 + 4 * lane;
        t[(d0 + 0) * 66 + jj] = (_Float16)a.x;
        t[(d0 + 1) * 66 + jj] = (_Float16)a.y;
        t[(d0 + 2) * 66 + jj] = (_Float16)a.z;
        t[(d0 + 3) * 66 + jj] = (_Float16)a.w;
        t[(d1 + 0) * 66 + jj] = (_Float16)c.x;
        t[(d1 + 1) * 66 + jj] = (_Float16)c.y;
        t[(d1 + 2) * 66 + jj] = (_Float16)c.z;
        t[(d1 + 3) * 66 + jj] = (_Float16)c.w;
    }
    __syncthreads();
    // store vT rows: 512 d x 8 chunks of 8 halves; 4B-aligned b32 LDS reads.
    #pragma unroll
    for (int it = 0; it < 16; ++it) {
        const int id = it * 256 + tid;
        const int d = id >> 3, ch = (id & 7) * 8;
        const uint32_t* tp = (const uint32_t*)&t[d * 66 + ch];
        uint4 v = {tp[0], tp[1], tp[2], tp[3]};
        *(uint4*)(vT + ((size_t)b * DD + d) * NN + j0 + ch) = v;
    }
}

// ---------------------------------------------------------------------------
// K2: W = exp( xhn xhn^T ), symmetric-triangular (inputs pre-normalized).
// 128x128 block, 4 waves 64x64, BK=64, double-buffered.
// NEW: counted-vmcnt schedule (T4): raw s_barrier, s_waitcnt vmcnt(8) keeps
// the next buffer's 8 loads in flight across the barrier (no vmcnt(0) drain
// in steady state); setprio(1) around MFMA cluster (T5).
// Epilogue unchanged: exp, register row/col sums -> denom atomics, two-phase
// symmetric store via LDS transposes.
// ---------------------------------------------------------------------------
__global__ __launch_bounds__(256) void k_scores(const _Float16* __restrict__ xhn,
                                                _Float16* __restrict__ W,
                                                float* __restrict__ denom) {
    __shared__ _Float16 smem[32768];          // 2 x (As 8192 + Bs 8192); epi: 128x136
    const int tid = threadIdx.x;
    const int lane = tid & 63, wv = tid >> 6;
    const int wr = wv >> 1, wc = wv & 1;
    const int m_ = lane & 15, quad = lane >> 4;
    const int b = blockIdx.z;

    int rem = blockIdx.x, ti = 0, rowlen = NN / 128;
    while (rem >= rowlen) { rem -= rowlen; ++ti; --rowlen; }
    const int tj = ti + rem;
    const int I = ti * 128, J = tj * 128;
    const bool diag = (ti == tj);

    const _Float16* Ab = xhn + ((size_t)b * NN + I) * DD;
    const _Float16* Bb = xhn + ((size_t)b * NN + J) * DD;

    f32x4 acc[4][4];
    #pragma unroll
    for (int i = 0; i < 4; ++i)
        #pragma unroll
        for (int j = 0; j < 4; ++j) acc[i][j] = (f32x4){0.f, 0.f, 0.f, 0.f};

    const int sub = lane >> 3;
    const int swc = (lane & 7) ^ sub;
    const _Float16* agl = Ab + (size_t)(wv * 32 + sub) * DD + swc * 8;
    const _Float16* bgl = Bb + (size_t)(wv * 32 + sub) * DD + swc * 8;

#define S_STAGE(kb_) do {                                                     \
    _Float16* A_ = smem + (((kb_) & 1) << 14);                                \
    const int k0_ = (kb_) * 64;                                               \
    _Pragma("unroll")                                                         \
    for (int c = 0; c < 4; ++c) {                                             \
        async_ld16(&A_[(wv * 32 + c * 8) * 64], agl + (size_t)c * 8 * DD + k0_); \
        async_ld16(&A_[8192 + (wv * 32 + c * 8) * 64], bgl + (size_t)c * 8 * DD + k0_); \
    } } while (0)

#define S_COMPUTE(kb_) do {                                                   \
    const _Float16* As_ = smem + (((kb_) & 1) << 14);                         \
    const _Float16* Bs_ = As_ + 8192;                                         \
    _Pragma("unroll")                                                         \
    for (int kc = 0; kc < 2; ++kc) {                                          \
        f16x8 af[4], bf[4];                                                   \
        _Pragma("unroll")                                                     \
        for (int t = 0; t < 4; ++t) {                                         \
            const int Ra = wr * 64 + t * 16 + m_;                             \
            const int Rb = wc * 64 + t * 16 + m_;                             \
            af[t] = *(const f16x8*)&As_[Ra * 64 + (((kc * 4 + quad) ^ (Ra & 7)) * 8)]; \
            bf[t] = *(const f16x8*)&Bs_[Rb * 64 + (((kc * 4 + quad) ^ (Rb & 7)) * 8)]; \
        }                                                                     \
        _Pragma("unroll")                                                     \
        for (int i = 0; i < 4; ++i)                                           \
            _Pragma("unroll")                                                 \
            for (int j = 0; j < 4; ++j)                                       \
                acc[i][j] = __builtin_amdgcn_mfma_f32_16x16x32_f16(af[i], bf[j], acc[i][j], 0, 0, 0); \
    } } while (0)

    S_STAGE(0); S_STAGE(1);
    for (int kb = 0; kb < DD / 64 - 1; ++kb) {
        VM_WAIT(8);                 // cur buffer's 8 loads done; next 8 stay in flight
        RAW_BAR();
        __builtin_amdgcn_s_setprio(1);
        S_COMPUTE(kb);
        __builtin_amdgcn_s_setprio(0);
        RAW_BAR();                  // all waves done reading cur buffer
        if (kb + 2 < DD / 64) S_STAGE(kb + 2);
    }
    VM_WAIT(0);
    RAW_BAR();
    __builtin_amdgcn_s_setprio(1);
    S_COMPUTE(DD / 64 - 1);
    __builtin_amdgcn_s_setprio(0);

    // Epilogue: exp into packed f16x4; register row/col sums.
    f16x4 wq[4][4];
    float rowpart[4][4];
    float colpart[4] = {0.f, 0.f, 0.f, 0.f};
    #pragma unroll
    for (int i = 0; i < 4; ++i)
        #pragma unroll
        for (int r = 0; r < 4; ++r) rowpart[i][r] = 0.f;

    #pragma unroll
    for (int i = 0; i < 4; ++i) {
        #pragma unroll
        for (int j = 0; j < 4; ++j) {
            #pragma unroll
            for (int r = 0; r < 4; ++r) {
                const float w = __expf(acc[i][j][r]);
                wq[i][j][r] = (_Float16)w;
                rowpart[i][r] += w;
                colpart[j] += w;
            }
        }
    }

    #pragma unroll
    for (int i = 0; i < 4; ++i) {
        #pragma unroll
        for (int r = 0; r < 4; ++r) {
            float s = rowpart[i][r];
            s += __shfl_xor(s, 1);
            s += __shfl_xor(s, 2);
            s += __shfl_xor(s, 4);
            s += __shfl_xor(s, 8);
            if (m_ == 0)
                atomicAdd(&denom[b * NN + I + wr * 64 + i * 16 + quad * 4 + r], s);
        }
    }
    if (!diag) {
        #pragma unroll
        for (int j = 0; j < 4; ++j) {
            float s = colpart[j];
            s += __shfl_xor(s, 16);
            s += __shfl_xor(s, 32);
            if (quad == 0)
                atomicAdd(&denom[b * NN + J + wc * 64 + j * 16 + m_], s);
        }
    }

    __syncthreads();   // all waves done with GEMM buffers before LDS reuse

    // Phase 1: WtT[col][row] (stride 136), b64 writes -> coalesced W(J,I).
    _Float16* WtT = smem;
    #pragma unroll
    for (int i = 0; i < 4; ++i) {
        const int rowb = wr * 64 + i * 16 + quad * 4;
        #pragma unroll
        for (int j = 0; j < 4; ++j) {
            const int col = wc * 64 + j * 16 + m_;
            *(f16x4*)&WtT[col * 136 + rowb] = wq[i][j];
        }
    }
    __syncthreads();
    {
        const int rr = tid >> 1, off = (tid & 1) * 64;
        _Float16* wg = W + ((size_t)b * NN + J + rr) * NN + I + off;
        const _Float16* wl = &WtT[rr * 136 + off];
        #pragma unroll
        for (int c = 0; c < 64; c += 8)
            *(uint4*)(wg + c) = *(const uint4*)(wl + c);
    }
    // Phase 2 (off-diag): row-major Wt -> coalesced W(I,J).
    if (!diag) {
        __syncthreads();
        _Float16* Wt = smem;
        #pragma unroll
        for (int i = 0; i < 4; ++i) {
            const int rowb = wr * 64 + i * 16 + quad * 4;
            #pragma unroll
            for (int j = 0; j < 4; ++j) {
                const int col = wc * 64 + j * 16 + m_;
                #pragma unroll
                for (int r = 0; r < 4; ++r)
                    Wt[(rowb + r) * 136 + col] = wq[i][j][r];
            }
        }
        __syncthreads();
        const int rr = tid >> 1, off = (tid & 1) * 64;
        _Float16* wg = W + ((size_t)b * NN + I + rr) * NN + J + off;
        const _Float16* wl = &Wt[rr * 136 + off];
        #pragma unroll
        for (int c = 0; c < 64; c += 8)
            *(uint4*)(wg + c) = *(const uint4*)(wl + c);
    }
#undef S_STAGE
#undef S_COMPUTE
}

// ---------------------------------------------------------------------------
// K3: O = (W @ V) * (1/denom_i), fp32 out.  FULL REWRITE:
// 256x256 tile, 8 waves (2Mx4N, per-wave 128x64 out), BK=64, K=2048 (32 steps)
// 128 KiB dynamic-LDS double buffer, counted vmcnt(8) + raw barriers (T3/T4),
// setprio around MFMA (T5), XOR-swizzled staging/reads (T2, conflict-free).
// grid (D/256=2, N/256=8, B=16) = 256 blocks = exactly 1/CU, zero tail.
// ---------------------------------------------------------------------------
__global__ __launch_bounds__(512, 2) void k_pv(const _Float16* __restrict__ W,
                                               const _Float16* __restrict__ vT,
                                               const float* __restrict__ denom,
                                               float* __restrict__ out) {
    extern __shared__ _Float16 smem[];        // 2 x (A 16384 + B 16384) halves = 128 KiB
    float* rdI = (float*)(smem + 65536);      // 256 floats after the buffers
    const int tid = threadIdx.x;
    const int lane = tid & 63, w = tid >> 6;  // 8 waves
    const int wr = w >> 2, wcol = w & 3;      // 2 x 4 wave grid
    const int m_ = lane & 15, quad = lane >> 4;
    const int b = blockIdx.z;
    const int D0 = blockIdx.x * 256;
    const int I  = blockIdx.y * 256;
    const _Float16* Ab = W  + ((size_t)b * NN + I) * NN;
    const _Float16* Bb = vT + ((size_t)b * DD + D0) * NN;

    const int sub = lane >> 3;
    const int swc = (lane & 7) ^ sub;
    const _Float16* agl = Ab + (size_t)(w * 32 + sub) * NN + swc * 8;
    const _Float16* bgl = Bb + (size_t)(w * 32 + sub) * NN + swc * 8;

    f32x4 acc[8][4];
    #pragma unroll
    for (int i = 0; i < 8; ++i)
        #pragma unroll
        for (int j = 0; j < 4; ++j) acc[i][j] = (f32x4){0.f, 0.f, 0.f, 0.f};

#define P_STAGE(kb_) do {                                                     \
    _Float16* A_ = smem + (((kb_) & 1) << 15);                                \
    const int k0_ = (kb_) * 64;                                               \
    _Pragma("unroll")                                                         \
    for (int c = 0; c < 4; ++c) {                                             \
        async_ld16(&A_[(w * 32 + c * 8) * 64], agl + (size_t)c * 8 * NN + k0_); \
        async_ld16(&A_[16384 + (w * 32 + c * 8) * 64], bgl + (size_t)c * 8 * NN + k0_); \
    } } while (0)

#define P_COMPUTE(kb_) do {                                                   \
    const _Float16* As_ = smem + (((kb_) & 1) << 15);                         \
    const _Float16* Bs_ = As_ + 16384;                                        \
    _Pragma("unroll")                                                         \
    for (int kc = 0; kc < 2; ++kc) {                                          \
        f16x8 af[8], bf[4];                                                   \
        _Pragma("unroll")                                                     \
        for (int i = 0; i < 8; ++i) {                                         \
            const int R = wr * 128 + i * 16 + m_;                             \
            af[i] = *(const f16x8*)&As_[R * 64 + (((kc * 4 + quad) ^ (R & 7)) * 8)]; \
        }                                                                     \
        _Pragma("unroll")                                                     \
        for (int j = 0; j < 4; ++j) {                                         \
            const int Rb = wcol * 64 + j * 16 + m_;                           \
            bf[j] = *(const f16x8*)&Bs_[Rb * 64 + (((kc * 4 + quad) ^ (Rb & 7)) * 8)]; \
        }                                                                     \
        _Pragma("unroll")                                                     \
        for (int i = 0; i < 8; ++i)                                           \
            _Pragma("unroll")                                                 \
            for (int j = 0; j < 4; ++j)                                       \
                acc[i][j] = __builtin_amdgcn_mfma_f32_16x16x32_f16(af[i], bf[j], acc[i][j], 0, 0, 0); \
    } } while (0)

    P_STAGE(0); P_STAGE(1);
    for (int kb = 0; kb < NN / 64 - 1; ++kb) {
        VM_WAIT(8);                 // cur buffer's 8 loads done; next 8 in flight
        RAW_BAR();
        __builtin_amdgcn_s_setprio(1);
        P_COMPUTE(kb);
        __builtin_amdgcn_s_setprio(0);
        RAW_BAR();                  // all waves done reading cur buffer
        if (kb + 2 < NN / 64) P_STAGE(kb + 2);
    }
    VM_WAIT(0);
    RAW_BAR();
    __builtin_amdgcn_s_setprio(1);
    P_COMPUTE(NN / 64 - 1);
    __builtin_amdgcn_s_setprio(0);

    // Epilogue: per-row reciprocal denominators via LDS broadcast, then store.
    if (tid < 256) rdI[tid] = 1.0f / denom[b * NN + I + tid];
    __syncthreads();

    #pragma unroll
    for (int i = 0; i < 8; ++i) {
        const int rowb = wr * 128 + i * 16 + quad * 4;
        #pragma unroll
        for (int r = 0; r < 4; ++r) {
            const float sc = rdI[rowb + r];
            float* op = out + ((size_t)(b * NN + I + rowb + r)) * DD + D0;
            #pragma unroll
            for (int j = 0; j < 4; ++j)
                op[wcol * 64 + j * 16 + m_] = acc[i][j][r] * sc;
        }
    }
#undef P_STAGE
#undef P_COMPUTE
}

// ---------------------------------------------------------------------------
extern "C" void kernel_launch(void* const* d_in, const int* in_sizes, int n_in,
                              void* d_out, int out_size, void* d_ws, size_t ws_size,
                              hipStream_t stream) {
    const float* x = (const float*)d_in[0];
    char* ws = (char*)d_ws;
    _Float16* xhn   = (_Float16*)(ws);                        // 32 MiB normalized fp16
    _Float16* vT    = (_Float16*)(ws + (size_t)33554432);     // 32 MiB fp16 x^T
    _Float16* W     = (_Float16*)(ws + (size_t)67108864);     // 128 MiB fp16 exp-scores
    float*    denom = (float*)   (ws + (size_t)201326592);    // 128 KiB
    float*    out   = (float*)d_out;

    k_prep<<<dim3(NN / 64, BB), 256, 0, stream>>>(x, xhn, vT, denom);
    const int npairs = (NN / 128) * (NN / 128 + 1) / 2;   // 136
    k_scores<<<dim3(npairs, 1, BB), 256, 0, stream>>>(xhn, W, denom);
    // 128 KiB LDS buffers + 1 KiB rdI, dynamic (exceeds 64 KiB static limit)
    k_pv<<<dim3(DD / 256, NN / 256, BB), 512, 132096, stream>>>(W, vT, denom, out);
}